// Round 4
// baseline (606.274 us; speedup 1.0000x reference)
//
#include <hip/hip_runtime.h>
#include <math.h>

#define NN 50000
#define EE 800000
#define D 128
#define EDIM 32
#define LL 3
#define NT 2
#define ET 3
#define NB 196       // ceil(NN/256)
#define NPAD 50080   // >= align64(c0) + c1 for any split; multiple of 32
#define NTILE 1565   // NPAD/32 (32-row wave tiles)
#define NBLKM 392    // ceil(NTILE/4), 4 waves/block

typedef _Float16 f16x8 __attribute__((ext_vector_type(8)));
typedef float f32x4 __attribute__((ext_vector_type(4)));

// split 8 consecutive fp32 into hi/lo f16 halves (hi + lo == x to ~2^-21 rel)
__device__ __forceinline__ void cvt8(const float4 u, const float4 v, f16x8& hi, f16x8& lo) {
    float x[8] = {u.x, u.y, u.z, u.w, v.x, v.y, v.z, v.w};
#pragma unroll
    for (int e = 0; e < 8; e++) {
        _Float16 h = (_Float16)x[e];
        hi[e] = h;
        lo[e] = (_Float16)(x[e] - (float)h);
    }
}

// ---------------- node-type permutation (deterministic, scan-based) ----------------
// packed counts: low 16 = type0, high 16 = type1 (totals <= 50000 < 65536)
__global__ __launch_bounds__(256) void k_pcount(const int* __restrict__ nt, int* __restrict__ pc) {
    __shared__ int s[256];
    int d = blockIdx.x * 256 + threadIdx.x;
    int ind = 0;
    if (d < NN) ind = (nt[d] == 0) ? 1 : 0x10000;
    s[threadIdx.x] = ind;
    __syncthreads();
    for (int st = 128; st; st >>= 1) {
        if (threadIdx.x < st) s[threadIdx.x] += s[threadIdx.x + st];
        __syncthreads();
    }
    if (threadIdx.x == 0) pc[blockIdx.x] = s[0];
}

__global__ __launch_bounds__(256) void k_pscan(const int* __restrict__ pc, int* __restrict__ po,
                                               int* __restrict__ meta) {
    __shared__ int s[256];
    int t = threadIdx.x;
    int v = (t < NB) ? pc[t] : 0;
    s[t] = v;
    __syncthreads();
    for (int st = 1; st < 256; st <<= 1) {
        int add = (t >= st) ? s[t - st] : 0;
        __syncthreads();
        s[t] += add;
        __syncthreads();
    }
    if (t < NB) po[t] = s[t] - v;                     // exclusive packed block offsets
    if (t == 0) {
        int tot = s[255];
        meta[3] = ((tot & 0xffff) + 63) & ~63;        // aligned base for type-1 region
    }
}

__global__ __launch_bounds__(256) void k_passign(const int* __restrict__ nt, const int* __restrict__ po,
                                                 const int* __restrict__ meta,
                                                 int* __restrict__ pos, int* __restrict__ inv) {
    __shared__ int s[256];
    int t = threadIdx.x;
    int d = blockIdx.x * 256 + t;
    int ty = (d < NN) ? nt[d] : -1;
    int ind = (ty == 0) ? 1 : ((ty == 1) ? 0x10000 : 0);
    s[t] = ind;
    __syncthreads();
    for (int st = 1; st < 256; st <<= 1) {
        int add = (t >= st) ? s[t - st] : 0;
        __syncthreads();
        s[t] += add;
        __syncthreads();
    }
    if (d >= NN) return;
    int excl = s[t] - ind;
    int pop = po[blockIdx.x];
    int p;
    if (ty == 0) p = (pop & 0xffff) + (excl & 0xffff);
    else         p = meta[3] + (pop >> 16) + (excl >> 16);
    pos[d] = p;
    inv[p] = d;
}

__global__ __launch_bounds__(256) void k_permx(const float* __restrict__ x, const int* __restrict__ pos,
                                               float* __restrict__ h0) {
    int flat = blockIdx.x * 256 + threadIdx.x;
    if (flat >= NN * 32) return;
    int d = flat >> 5, f4 = flat & 31;
    int p = pos[d];
    ((float4*)h0)[(size_t)p * 32 + f4] = ((const float4*)x)[(size_t)d * 32 + f4];
}

// ---------------- histogram of dst ----------------
__global__ __launch_bounds__(256) void k_hist(const int* __restrict__ dst, int* __restrict__ deg) {
    int e = blockIdx.x * 256 + threadIdx.x;
    if (e < EE) atomicAdd(&deg[dst[e]], 1);
}

// ---------------- 2-level exclusive scan ----------------
__global__ __launch_bounds__(256) void k_scan_bsum(const int* __restrict__ deg, int* __restrict__ bsum) {
    __shared__ int s[256];
    int t = threadIdx.x;
    int d = blockIdx.x * 256 + t;
    s[t] = (d < NN) ? deg[d] : 0;
    __syncthreads();
    for (int st = 128; st > 0; st >>= 1) {
        if (t < st) s[t] += s[t + st];
        __syncthreads();
    }
    if (t == 0) bsum[blockIdx.x] = s[0];
}

__global__ __launch_bounds__(256) void k_scan_boff(const int* __restrict__ bsum, int* __restrict__ boff) {
    __shared__ int s[256];
    int t = threadIdx.x;
    s[t] = (t < NB) ? bsum[t] : 0;
    __syncthreads();
    for (int st = 1; st < 256; st <<= 1) {
        int add = (t >= st) ? s[t - st] : 0;
        __syncthreads();
        s[t] += add;
        __syncthreads();
    }
    if (t < NB) boff[t] = (t == 0) ? 0 : s[t - 1];
}

__global__ __launch_bounds__(256) void k_scan_offs(const int* __restrict__ deg, const int* __restrict__ boff,
                                                   int* __restrict__ offs, int* __restrict__ cur) {
    __shared__ int s[256];
    int t = threadIdx.x;
    int d = blockIdx.x * 256 + t;
    int v = (d < NN) ? deg[d] : 0;
    s[t] = v;
    __syncthreads();
    for (int st = 1; st < 256; st <<= 1) {
        int add = (t >= st) ? s[t - st] : 0;
        __syncthreads();
        s[t] += add;
        __syncthreads();
    }
    if (d < NN) {
        int excl = s[t] - v + boff[blockIdx.x];
        offs[d] = excl;
        cur[d]  = excl;
    }
}

// ------------- per-edge scalars: 2 edges/thread, 16B records, bias via per-node atomics -------------
// Record: float4(src_pos_bits, A0, A1, A2) scattered to dst-sorted position (half the
// write amplification of the 32B record). B (pump edges only, ~1/3) accumulates into
// sBn[l*NN + dst] with 3 scalar atomicAdds (validated in round 2).
// LDS weight stride 33 keeps the 3 edge-type rows in distinct banks (verified -> 0 conflicts).
__global__ __launch_bounds__(256) void k_edge(const float* __restrict__ edge_attr,
                                              const float* __restrict__ edge_W,
                                              const float* __restrict__ edge_b,
                                              const float* __restrict__ emb,
                                              const int* __restrict__ ei,
                                              const int* __restrict__ etype,
                                              const int* __restrict__ pos,
                                              int* __restrict__ cur,
                                              float4* __restrict__ esort,
                                              float* __restrict__ sBn) {
    __shared__ float eWl[18 * 33];   // 18 rows x 32 floats, stride 33
    __shared__ float ebd[18];        // emb·eW + eb
    int t0 = threadIdx.x;
    for (int i = t0; i < 18 * EDIM; i += 256) eWl[(i >> 5) * 33 + (i & 31)] = edge_W[i];
    __syncthreads();
    if (t0 < 18) {
        int l = t0 / (ET * 2);
        int rem = t0 % (ET * 2);
        int tt = rem / 2;
        float sum = edge_b[t0];
        const float* em = emb + (l * ET + tt) * EDIM;
        const float* wq = eWl + t0 * 33;
        for (int c = 0; c < EDIM; c++) sum += em[c] * wq[c];
        ebd[t0] = sum;
    }
    __syncthreads();

    int eA = blockIdx.x * 512 + t0;       // always < EE (grid = ceil(EE/512), EE%512==256... guarded anyway)
    int eB = eA + 256;
    bool vA = (eA < EE);
    bool vB = (eB < EE);
    int eAc = vA ? eA : 0;
    int eBc = vB ? eB : eAc;

    // ---- issue ALL long-latency loads for both edges up front ----
    float a0[EDIM], a1[EDIM];
    {
        const float4* ap = (const float4*)(edge_attr + (size_t)eAc * EDIM);
#pragma unroll
        for (int i = 0; i < EDIM / 4; i++) {
            float4 v = ap[i];
            a0[4 * i + 0] = v.x; a0[4 * i + 1] = v.y; a0[4 * i + 2] = v.z; a0[4 * i + 3] = v.w;
        }
    }
    {
        const float4* ap = (const float4*)(edge_attr + (size_t)eBc * EDIM);
#pragma unroll
        for (int i = 0; i < EDIM / 4; i++) {
            float4 v = ap[i];
            a1[4 * i + 0] = v.x; a1[4 * i + 1] = v.y; a1[4 * i + 2] = v.z; a1[4 * i + 3] = v.w;
        }
    }
    int ttA = etype[eAc],   ttB = etype[eBc];
    int srcA = ei[eAc],     srcB = ei[eBc];
    int dstA = ei[EE + eAc], dstB = ei[EE + eBc];
    int spA = pos[srcA],    spB = pos[srcB];
    int pA = vA ? atomicAdd(&cur[dstA], 1) : 0;
    int pB = vB ? atomicAdd(&cur[dstB], 1) : 0;

    float dirA = a0[EDIM - 2], pumpA = a0[EDIM - 1];
    float dirB = a1[EDIM - 2], pumpB = a1[EDIM - 1];
    float signA = dirA * 2.f - 1.f, signB = dirB * 2.f - 1.f;
    float speedA = pumpA * (dirA > 0.f ? dirA : 1.f);
    float speedB = pumpB * (dirB > 0.f ? dirB : 1.f);

    float AvA[LL], BvA[LL], AvB[LL], BvB[LL];
#pragma unroll
    for (int l = 0; l < LL; l++) {
        const float* w0A = eWl + ((l * ET + ttA) * 2 + 0) * 33;
        const float* w1A = w0A + 33;
        const float* w0B = eWl + ((l * ET + ttB) * 2 + 0) * 33;
        const float* w1B = w0B + 33;
        float r0A = ebd[(l * ET + ttA) * 2 + 0];
        float r1A = ebd[(l * ET + ttA) * 2 + 1];
        float r0B = ebd[(l * ET + ttB) * 2 + 0];
        float r1B = ebd[(l * ET + ttB) * 2 + 1];
#pragma unroll
        for (int c = 0; c < EDIM; c++) {
            r0A += a0[c] * w0A[c]; r1A += a0[c] * w1A[c];
            r0B += a1[c] * w0B[c]; r1B += a1[c] * w1B[c];
        }
        float gA = fmaxf(r0A, 0.f) + log1pf(expf(-fabsf(r0A)));   // stable softplus
        float gB = fmaxf(r0B, 0.f) + log1pf(expf(-fabsf(r0B)));
        float biA = 0.f, biB = 0.f;
        if (ttA == 1) { gA *= speedA; biA = r1A * speedA; }       // PUMP == 1
        if (ttB == 1) { gB *= speedB; biB = r1B * speedB; }
        AvA[l] = signA * gA; BvA[l] = signA * biA;
        AvB[l] = signB * gB; BvB[l] = signB * biB;
    }

    if (vA) {
        esort[pA] = make_float4(__int_as_float(spA), AvA[0], AvA[1], AvA[2]);
        if (ttA == 1) {
#pragma unroll
            for (int l = 0; l < LL; l++) atomicAdd(&sBn[l * NN + dstA], BvA[l]);
        }
    }
    if (vB) {
        esort[pB] = make_float4(__int_as_float(spB), AvB[0], AvB[1], AvB[2]);
        if (ttB == 1) {
#pragma unroll
            for (int l = 0; l < LL; l++) atomicAdd(&sBn[l * NN + dstB], BvB[l]);
        }
    }
}

// ------------- gather: aggr[pos[d]] = sum A*h[spos] - sA*h[pos[d]] + sBn[d] -------------
// 2 nodes / block; per node 4 edge-workers x 32 float4-lanes; 4 edges in flight per worker
// (stride 16 covers the average degree in one iteration -> 16 random row-fetches in flight/node).
__global__ __launch_bounds__(256) void k_gather(const float* __restrict__ h,
                                                const int* __restrict__ offs,
                                                const int* __restrict__ deg,
                                                const int* __restrict__ pos,
                                                const float4* __restrict__ esort,
                                                const float* __restrict__ sBn,
                                                int layer,
                                                float* __restrict__ aggr) {
    __shared__ float4 rbuf[2][32];
    __shared__ float  rsum[2];
    int local = threadIdx.x;
    int nb = local >> 7;                    // node within block
    int node = blockIdx.x * 2 + nb;
    int t = local & 127;
    int w = t >> 5;                         // worker 0..3
    int f4 = t & 31;                        // feature-quad lane
    int start = offs[node];
    int n = deg[node];
    int p = pos[node];

    float4 acc = make_float4(0.f, 0.f, 0.f, 0.f);
    float sA = 0.f;
    for (int k = w; k < n; k += 16) {
        float4 e[4];
#pragma unroll
        for (int u = 0; u < 4; u++) {
            int ku = k + 4 * u;
            e[u] = esort[(ku < n) ? (size_t)(start + ku) : (size_t)start];
        }
        float4 hv[4];
#pragma unroll
        for (int u = 0; u < 4; u++) {
            int s = __float_as_int(e[u].x);
            hv[u] = *(const float4*)&h[(size_t)s * D + 4 * f4];
        }
#pragma unroll
        for (int u = 0; u < 4; u++) {
            int ku = k + 4 * u;
            float A = (layer == 0) ? e[u].y : ((layer == 1) ? e[u].z : e[u].w);
            if (ku >= n) A = 0.f;
            acc.x += A * hv[u].x; acc.y += A * hv[u].y;
            acc.z += A * hv[u].z; acc.w += A * hv[u].w;
            sA += A;
        }
    }
    // combine worker pairs within wave (lanes l and l^32)
    acc.x += __shfl_xor(acc.x, 32); acc.y += __shfl_xor(acc.y, 32);
    acc.z += __shfl_xor(acc.z, 32); acc.w += __shfl_xor(acc.w, 32);
    sA += __shfl_xor(sA, 32);
    // cross-wave combine via LDS: upper wave of each node writes, lower reads
    if (((local >> 6) & 1) == 1 && (t & 63) < 32) {
        rbuf[nb][f4] = acc;
        if (f4 == 0) rsum[nb] = sA;
    }
    __syncthreads();
    if (((local >> 6) & 1) == 0 && (t & 63) < 32) {
        float4 o = rbuf[nb][f4];
        float sAt = sA + rsum[nb];
        float sBt = sBn[layer * NN + node];
        float4 hd = *(const float4*)&h[(size_t)p * D + 4 * f4];
        float4 r;
        r.x = acc.x + o.x - sAt * hd.x + sBt;
        r.y = acc.y + o.y - sAt * hd.y + sBt;
        r.z = acc.z + o.z - sAt * hd.z + sBt;
        r.w = acc.w + o.w - sAt * hd.w + sBt;
        *(float4*)&aggr[(size_t)p * D + 4 * f4] = r;
    }
}

// ------------- node transform + ReLU + LayerNorm + residual --------------------------
// MFMA split-f16 GEMM: one wave owns a 32x128 output tile; no LDS, no barriers.
__global__ __launch_bounds__(256) void k_node(const float* __restrict__ aggr,
                                              const float* __restrict__ hprev,
                                              const float* __restrict__ Wg,   // node_W + l*NT*D*D
                                              const float* __restrict__ bg,   // node_b + l*NT*D
                                              const float* __restrict__ lng,
                                              const float* __restrict__ lnb,
                                              const int* __restrict__ meta,
                                              float* __restrict__ hnext) {
    int wid  = threadIdx.x >> 6;
    int lane = threadIdx.x & 63;
    int w0 = (blockIdx.x * 4 + wid) * 32;          // first row of this wave's tile
    if (w0 >= NPAD) return;
    int l15 = lane & 15, lg = lane >> 4;
    int tt = (w0 >= meta[3]) ? 1 : 0;              // meta[3] is 64-aligned, w0 is 32-aligned
    const float* W = Wg + (size_t)tt * D * D;

    f32x4 acc[2][8];
#pragma unroll
    for (int i = 0; i < 2; i++)
#pragma unroll
        for (int j = 0; j < 8; j++) acc[i][j] = (f32x4){0.f, 0.f, 0.f, 0.f};

#pragma unroll 1
    for (int ks = 0; ks < 4; ks++) {
        int kb = ks * 32 + 8 * lg;                 // float offset within row
        float4 rA[2][2], rB[8][2];
#pragma unroll
        for (int i = 0; i < 2; i++) {
            const float* p = aggr + (size_t)(w0 + 16 * i + l15) * D + kb;
            rA[i][0] = *(const float4*)p;
            rA[i][1] = *(const float4*)(p + 4);
        }
#pragma unroll
        for (int j = 0; j < 8; j++) {
            const float* p = W + (size_t)(16 * j + l15) * D + kb;
            rB[j][0] = *(const float4*)p;
            rB[j][1] = *(const float4*)(p + 4);
        }
        f16x8 ahi[2], alo[2];
#pragma unroll
        for (int i = 0; i < 2; i++) cvt8(rA[i][0], rA[i][1], ahi[i], alo[i]);
#pragma unroll
        for (int j = 0; j < 8; j++) {
            f16x8 bhi, blo;
            cvt8(rB[j][0], rB[j][1], bhi, blo);
#pragma unroll
            for (int i = 0; i < 2; i++) {
                acc[i][j] = __builtin_amdgcn_mfma_f32_16x16x32_f16(ahi[i], bhi, acc[i][j], 0, 0, 0);
                acc[i][j] = __builtin_amdgcn_mfma_f32_16x16x32_f16(alo[i], bhi, acc[i][j], 0, 0, 0);
                acc[i][j] = __builtin_amdgcn_mfma_f32_16x16x32_f16(ahi[i], blo, acc[i][j], 0, 0, 0);
            }
        }
    }

    // epilogue: bias + relu + LN (wave-local: full 128-wide row lives in one 16-lane group) + residual
    float bv[8], gv[8], bb[8];
#pragma unroll
    for (int j = 0; j < 8; j++) {
        int col = 16 * j + l15;
        bv[j] = bg[tt * D + col];
        gv[j] = lng[col];
        bb[j] = lnb[col];
    }
#pragma unroll
    for (int i = 0; i < 2; i++)
#pragma unroll
        for (int j = 0; j < 8; j++)
#pragma unroll
            for (int r = 0; r < 4; r++)
                acc[i][j][r] = fmaxf(acc[i][j][r] + bv[j], 0.f);

    float mu[2][4], rs[2][4];
#pragma unroll
    for (int i = 0; i < 2; i++)
#pragma unroll
        for (int r = 0; r < 4; r++) {
            float s = 0.f, s2 = 0.f;
#pragma unroll
            for (int j = 0; j < 8; j++) { float v = acc[i][j][r]; s += v; s2 += v * v; }
#pragma unroll
            for (int m = 1; m < 16; m <<= 1) { s += __shfl_xor(s, m); s2 += __shfl_xor(s2, m); }
            float mm = s * (1.f / 128.f);
            mu[i][r] = mm;
            rs[i][r] = rsqrtf(s2 * (1.f / 128.f) - mm * mm + 1e-5f);
        }

#pragma unroll
    for (int i = 0; i < 2; i++)
#pragma unroll
        for (int r = 0; r < 4; r++) {
            int row = w0 + 16 * i + 4 * lg + r;
#pragma unroll
            for (int j = 0; j < 8; j++) {
                int col = 16 * j + l15;
                float v = (acc[i][j][r] - mu[i][r]) * rs[i][r] * gv[j] + bb[j]
                          + hprev[(size_t)row * D + col];
                hnext[(size_t)row * D + col] = v;
            }
        }
}

// ------------- final FC with un-permute (same MFMA structure, scatter epilogue) -------------
__global__ __launch_bounds__(256) void k_fc(const float* __restrict__ hin,
                                            const float* __restrict__ W,
                                            const float* __restrict__ bias,
                                            const int* __restrict__ inv,
                                            float* __restrict__ out) {
    int wid  = threadIdx.x >> 6;
    int lane = threadIdx.x & 63;
    int w0 = (blockIdx.x * 4 + wid) * 32;
    if (w0 >= NPAD) return;
    int l15 = lane & 15, lg = lane >> 4;

    f32x4 acc[2][8];
#pragma unroll
    for (int i = 0; i < 2; i++)
#pragma unroll
        for (int j = 0; j < 8; j++) acc[i][j] = (f32x4){0.f, 0.f, 0.f, 0.f};

#pragma unroll 1
    for (int ks = 0; ks < 4; ks++) {
        int kb = ks * 32 + 8 * lg;
        float4 rA[2][2], rB[8][2];
#pragma unroll
        for (int i = 0; i < 2; i++) {
            const float* p = hin + (size_t)(w0 + 16 * i + l15) * D + kb;
            rA[i][0] = *(const float4*)p;
            rA[i][1] = *(const float4*)(p + 4);
        }
#pragma unroll
        for (int j = 0; j < 8; j++) {
            const float* p = W + (size_t)(16 * j + l15) * D + kb;
            rB[j][0] = *(const float4*)p;
            rB[j][1] = *(const float4*)(p + 4);
        }
        f16x8 ahi[2], alo[2];
#pragma unroll
        for (int i = 0; i < 2; i++) cvt8(rA[i][0], rA[i][1], ahi[i], alo[i]);
#pragma unroll
        for (int j = 0; j < 8; j++) {
            f16x8 bhi, blo;
            cvt8(rB[j][0], rB[j][1], bhi, blo);
#pragma unroll
            for (int i = 0; i < 2; i++) {
                acc[i][j] = __builtin_amdgcn_mfma_f32_16x16x32_f16(ahi[i], bhi, acc[i][j], 0, 0, 0);
                acc[i][j] = __builtin_amdgcn_mfma_f32_16x16x32_f16(alo[i], bhi, acc[i][j], 0, 0, 0);
                acc[i][j] = __builtin_amdgcn_mfma_f32_16x16x32_f16(ahi[i], blo, acc[i][j], 0, 0, 0);
            }
        }
    }

    float bv[8];
#pragma unroll
    for (int j = 0; j < 8; j++) bv[j] = bias[16 * j + l15];

#pragma unroll
    for (int i = 0; i < 2; i++)
#pragma unroll
        for (int r = 0; r < 4; r++) {
            int row = w0 + 16 * i + 4 * lg + r;
            int orig = inv[row];
            if (orig >= 0) {
#pragma unroll
                for (int j = 0; j < 8; j++)
                    out[(size_t)orig * D + 16 * j + l15] = acc[i][j][r] + bv[j];
            }
        }
}

extern "C" void kernel_launch(void* const* d_in, const int* in_sizes, int n_in,
                              void* d_out, int out_size, void* d_ws, size_t ws_size,
                              hipStream_t stream) {
    const float* x         = (const float*)d_in[0];
    const float* edge_attr = (const float*)d_in[1];
    const float* node_W    = (const float*)d_in[2];
    const float* node_b    = (const float*)d_in[3];
    const float* edge_W    = (const float*)d_in[4];
    const float* edge_b    = (const float*)d_in[5];
    const float* emb       = (const float*)d_in[6];
    const float* ln_g      = (const float*)d_in[7];
    const float* ln_b      = (const float*)d_in[8];
    const float* fc_W      = (const float*)d_in[9];
    const float* fc_b      = (const float*)d_in[10];
    const int*   edge_index = (const int*)d_in[11];
    const int*   node_type  = (const int*)d_in[12];
    const int*   edge_type  = (const int*)d_in[13];
    float* out = (float*)d_out;

    char* w = (char*)d_ws;
    auto alloc = [&](size_t bytes) {
        void* p = (void*)w;
        w += (bytes + 255) & ~(size_t)255;
        return p;
    };
    float*  P     = (float*)alloc((size_t)NPAD * D * 4);   // permuted x / layer buffers
    float*  Q     = (float*)alloc((size_t)NPAD * D * 4);
    float*  G     = (float*)alloc((size_t)NPAD * D * 4);   // aggr
    float4* esort = (float4*)alloc((size_t)EE * 16);       // 16B records (sp, A0, A1, A2)
    float*  sBn   = (float*)alloc((size_t)LL * NN * 4);    // per-layer per-node bias sums
    int*    pos   = (int*)alloc((size_t)NN * 4);
    int*    inv   = (int*)alloc((size_t)NPAD * 4);
    int*    deg   = (int*)alloc((size_t)NN * 4);
    int*    offs  = (int*)alloc((size_t)NN * 4);
    int*    cur   = (int*)alloc((size_t)NN * 4);
    int*    bsum  = (int*)alloc(256 * 4);
    int*    boff  = (int*)alloc(256 * 4);
    int*    pc    = (int*)alloc(256 * 4);
    int*    po    = (int*)alloc(256 * 4);
    int*    meta  = (int*)alloc(8 * 4);

    hipMemsetAsync(deg, 0, (size_t)NN * 4, stream);
    hipMemsetAsync(inv, 0xFF, (size_t)NPAD * 4, stream);   // -1 = "gap row", k_fc skips
    hipMemsetAsync(sBn, 0, (size_t)LL * NN * 4, stream);

    k_pcount<<<NB, 256, 0, stream>>>(node_type, pc);
    k_pscan<<<1, 256, 0, stream>>>(pc, po, meta);
    k_passign<<<NB, 256, 0, stream>>>(node_type, po, meta, pos, inv);
    k_permx<<<(NN * 32 + 255) / 256, 256, 0, stream>>>(x, pos, P);

    k_hist<<<(EE + 255) / 256, 256, 0, stream>>>(edge_index + EE, deg);
    k_scan_bsum<<<NB, 256, 0, stream>>>(deg, bsum);
    k_scan_boff<<<1, 256, 0, stream>>>(bsum, boff);
    k_scan_offs<<<NB, 256, 0, stream>>>(deg, boff, offs, cur);
    k_edge<<<(EE + 511) / 512, 256, 0, stream>>>(edge_attr, edge_W, edge_b, emb,
                                                 edge_index, edge_type, pos, cur, esort, sBn);

    // layer rotation: P -> Q -> P -> Q   (in, out per layer)
    const float* hin = P;
    float* outs[LL] = {Q, P, Q};
    for (int l = 0; l < LL; l++) {
        k_gather<<<NN / 2, 256, 0, stream>>>(hin, offs, deg, pos, esort, sBn, l, G);
        k_node<<<NBLKM, 256, 0, stream>>>(G, hin,
                                          node_W + (size_t)l * NT * D * D,
                                          node_b + (size_t)l * NT * D,
                                          ln_g + (size_t)l * D,
                                          ln_b + (size_t)l * D,
                                          meta, outs[l]);
        hin = outs[l];
    }
    k_fc<<<NBLKM, 256, 0, stream>>>(hin, fc_W, fc_b, inv, out);
}

// Round 5
// 586.251 us; speedup vs baseline: 1.0342x; 1.0342x over previous
//
#include <hip/hip_runtime.h>
#include <math.h>

#define NN 50000
#define EE 800000
#define D 128
#define EDIM 32
#define LL 3
#define NT 2
#define ET 3
#define NB 196       // ceil(NN/256)
#define NPAD 50080   // >= align64(c0) + c1 for any split; multiple of 32
#define NTILE 1565   // NPAD/32 (32-row wave tiles)
#define NBLKM 392    // ceil(NTILE/4), 4 waves/block

typedef _Float16 f16x8 __attribute__((ext_vector_type(8)));
typedef float f32x4 __attribute__((ext_vector_type(4)));

// split 8 consecutive fp32 into hi/lo f16 halves (hi + lo == x to ~2^-21 rel)
__device__ __forceinline__ void cvt8(const float4 u, const float4 v, f16x8& hi, f16x8& lo) {
    float x[8] = {u.x, u.y, u.z, u.w, v.x, v.y, v.z, v.w};
#pragma unroll
    for (int e = 0; e < 8; e++) {
        _Float16 h = (_Float16)x[e];
        hi[e] = h;
        lo[e] = (_Float16)(x[e] - (float)h);
    }
}

// ---------------- node-type permutation (deterministic, scan-based) ----------------
// packed counts: low 16 = type0, high 16 = type1 (totals <= 50000 < 65536)
__global__ __launch_bounds__(256) void k_pcount(const int* __restrict__ nt, int* __restrict__ pc) {
    __shared__ int s[256];
    int d = blockIdx.x * 256 + threadIdx.x;
    int ind = 0;
    if (d < NN) ind = (nt[d] == 0) ? 1 : 0x10000;
    s[threadIdx.x] = ind;
    __syncthreads();
    for (int st = 128; st; st >>= 1) {
        if (threadIdx.x < st) s[threadIdx.x] += s[threadIdx.x + st];
        __syncthreads();
    }
    if (threadIdx.x == 0) pc[blockIdx.x] = s[0];
}

__global__ __launch_bounds__(256) void k_pscan(const int* __restrict__ pc, int* __restrict__ po,
                                               int* __restrict__ meta) {
    __shared__ int s[256];
    int t = threadIdx.x;
    int v = (t < NB) ? pc[t] : 0;
    s[t] = v;
    __syncthreads();
    for (int st = 1; st < 256; st <<= 1) {
        int add = (t >= st) ? s[t - st] : 0;
        __syncthreads();
        s[t] += add;
        __syncthreads();
    }
    if (t < NB) po[t] = s[t] - v;                     // exclusive packed block offsets
    if (t == 0) {
        int tot = s[255];
        meta[3] = ((tot & 0xffff) + 63) & ~63;        // aligned base for type-1 region
    }
}

__global__ __launch_bounds__(256) void k_passign(const int* __restrict__ nt, const int* __restrict__ po,
                                                 const int* __restrict__ meta,
                                                 int* __restrict__ pos, int* __restrict__ inv) {
    __shared__ int s[256];
    int t = threadIdx.x;
    int d = blockIdx.x * 256 + t;
    int ty = (d < NN) ? nt[d] : -1;
    int ind = (ty == 0) ? 1 : ((ty == 1) ? 0x10000 : 0);
    s[t] = ind;
    __syncthreads();
    for (int st = 1; st < 256; st <<= 1) {
        int add = (t >= st) ? s[t - st] : 0;
        __syncthreads();
        s[t] += add;
        __syncthreads();
    }
    if (d >= NN) return;
    int excl = s[t] - ind;
    int pop = po[blockIdx.x];
    int p;
    if (ty == 0) p = (pop & 0xffff) + (excl & 0xffff);
    else         p = meta[3] + (pop >> 16) + (excl >> 16);
    pos[d] = p;
    inv[p] = d;
}

__global__ __launch_bounds__(256) void k_permx(const float* __restrict__ x, const int* __restrict__ pos,
                                               float* __restrict__ h0) {
    int flat = blockIdx.x * 256 + threadIdx.x;
    if (flat >= NN * 32) return;
    int d = flat >> 5, f4 = flat & 31;
    int p = pos[d];
    ((float4*)h0)[(size_t)p * 32 + f4] = ((const float4*)x)[(size_t)d * 32 + f4];
}

// ---------------- histogram of dst + within-destination rank ----------------
// The atomic's return value IS the rank of edge e among edges sharing its dst;
// persisting it (coalesced 4B store) lets k_edge compute its scatter position
// as offs[dst]+rank[e] with NO second contended atomic pass.
__global__ __launch_bounds__(256) void k_hist(const int* __restrict__ dst, int* __restrict__ deg,
                                              int* __restrict__ rank) {
    int e = blockIdx.x * 256 + threadIdx.x;
    if (e < EE) {
        int r = atomicAdd(&deg[dst[e]], 1);
        rank[e] = r;
    }
}

// ---------------- 2-level exclusive scan ----------------
__global__ __launch_bounds__(256) void k_scan_bsum(const int* __restrict__ deg, int* __restrict__ bsum) {
    __shared__ int s[256];
    int t = threadIdx.x;
    int d = blockIdx.x * 256 + t;
    s[t] = (d < NN) ? deg[d] : 0;
    __syncthreads();
    for (int st = 128; st > 0; st >>= 1) {
        if (t < st) s[t] += s[t + st];
        __syncthreads();
    }
    if (t == 0) bsum[blockIdx.x] = s[0];
}

__global__ __launch_bounds__(256) void k_scan_boff(const int* __restrict__ bsum, int* __restrict__ boff) {
    __shared__ int s[256];
    int t = threadIdx.x;
    s[t] = (t < NB) ? bsum[t] : 0;
    __syncthreads();
    for (int st = 1; st < 256; st <<= 1) {
        int add = (t >= st) ? s[t - st] : 0;
        __syncthreads();
        s[t] += add;
        __syncthreads();
    }
    if (t < NB) boff[t] = (t == 0) ? 0 : s[t - 1];
}

__global__ __launch_bounds__(256) void k_scan_offs(const int* __restrict__ deg, const int* __restrict__ boff,
                                                   int* __restrict__ offs) {
    __shared__ int s[256];
    int t = threadIdx.x;
    int d = blockIdx.x * 256 + t;
    int v = (d < NN) ? deg[d] : 0;
    s[t] = v;
    __syncthreads();
    for (int st = 1; st < 256; st <<= 1) {
        int add = (t >= st) ? s[t - st] : 0;
        __syncthreads();
        s[t] += add;
        __syncthreads();
    }
    if (d < NN) offs[d] = s[t] - v + boff[blockIdx.x];
}

// ------------- per-edge scalars (all 3 layers) packed + scattered into dst-sorted order -------------
// Scatter position = offs[dst] + rank[e] (precomputed by k_hist) -> no contended atomic here.
// LDS weight rows padded to stride 33 so the 3 edge-type rows land in distinct banks.
__global__ __launch_bounds__(256) void k_edge(const float* __restrict__ edge_attr,
                                              const float* __restrict__ edge_W,
                                              const float* __restrict__ edge_b,
                                              const float* __restrict__ emb,
                                              const int* __restrict__ ei,
                                              const int* __restrict__ etype,
                                              const int* __restrict__ pos,
                                              const int* __restrict__ offs,
                                              const int* __restrict__ rank,
                                              float4* __restrict__ esort) {
    __shared__ float eWl[18 * 33];   // 18 rows x 32 floats, stride 33
    __shared__ float ebd[18];        // emb·eW + eb
    int t0 = threadIdx.x;
    for (int i = t0; i < 18 * EDIM; i += 256) eWl[(i >> 5) * 33 + (i & 31)] = edge_W[i];
    __syncthreads();
    if (t0 < 18) {
        int l = t0 / (ET * 2);
        int rem = t0 % (ET * 2);
        int tt = rem / 2;
        float sum = edge_b[t0];
        const float* em = emb + (l * ET + tt) * EDIM;
        const float* wq  = eWl + t0 * 33;
        for (int c = 0; c < EDIM; c++) sum += em[c] * wq[c];
        ebd[t0] = sum;
    }
    __syncthreads();
    int e = blockIdx.x * 256 + t0;
    if (e >= EE) return;

    float a[EDIM];
    const float4* ap = (const float4*)(edge_attr + (size_t)e * EDIM);
#pragma unroll
    for (int i = 0; i < EDIM / 4; i++) {
        float4 v = ap[i];
        a[4 * i + 0] = v.x; a[4 * i + 1] = v.y; a[4 * i + 2] = v.z; a[4 * i + 3] = v.w;
    }
    int tt = etype[e];
    float dir  = a[EDIM - 2];
    float pump = a[EDIM - 1];
    float sign = dir * 2.f - 1.f;
    float speed = pump * (dir > 0.f ? dir : 1.f);
    int src = ei[e];
    int dst = ei[EE + e];
    int sp = pos[src];
    int p = offs[dst] + rank[e];
    float Av[LL], Bv[LL];
#pragma unroll
    for (int l = 0; l < LL; l++) {
        const float* w0 = eWl + ((l * ET + tt) * 2 + 0) * 33;
        const float* w1 = w0 + 33;
        float r0 = ebd[(l * ET + tt) * 2 + 0];
        float r1 = ebd[(l * ET + tt) * 2 + 1];
#pragma unroll
        for (int c = 0; c < EDIM; c++) { r0 += a[c] * w0[c]; r1 += a[c] * w1[c]; }
        float gain = fmaxf(r0, 0.f) + log1pf(expf(-fabsf(r0)));   // stable softplus
        float bias = 0.f;
        if (tt == 1) { gain *= speed; bias = r1 * speed; }        // PUMP == 1
        Av[l] = sign * gain;
        Bv[l] = sign * bias;
    }
    float4 e0 = make_float4(__int_as_float(sp), Av[0], Av[1], Av[2]);
    float4 e1 = make_float4(Bv[0], Bv[1], Bv[2], 0.f);
    esort[(size_t)p * 2 + 0] = e0;
    esort[(size_t)p * 2 + 1] = e1;
}

// ------------- gather: aggr[pos[d]] = sum A*h[spos] - sA*h[pos[d]] + sB -------------
// 2 nodes / block; per node 4 edge-workers x 32 float4-lanes.
// 4 edges in flight per worker (stride 16 covers the average degree in one iteration
// -> ~16 random row-fetches in flight per node in the latency-bound regime).
__global__ __launch_bounds__(256) void k_gather(const float* __restrict__ h,
                                                const int* __restrict__ offs,
                                                const int* __restrict__ deg,
                                                const int* __restrict__ pos,
                                                const float4* __restrict__ esort,
                                                int layer,
                                                float* __restrict__ aggr) {
    __shared__ float4 rbuf[2][32];
    __shared__ float  rsum[2][2];
    int local = threadIdx.x;
    int nb = local >> 7;                    // node within block
    int node = blockIdx.x * 2 + nb;
    int t = local & 127;
    int w = t >> 5;                         // worker 0..3
    int f4 = t & 31;                        // feature-quad lane
    int start = offs[node];
    int n = deg[node];
    int p = pos[node];

    float4 acc = make_float4(0.f, 0.f, 0.f, 0.f);
    float sA = 0.f, sB = 0.f;
    for (int k = w; k < n; k += 16) {
        float4 e0[4], e1[4];
#pragma unroll
        for (int u = 0; u < 4; u++) {
            int ku = k + 4 * u;
            size_t idx = (ku < n) ? (size_t)(start + ku) * 2 : (size_t)start * 2;
            e0[u] = esort[idx];
            e1[u] = esort[idx + 1];
        }
        float4 hv[4];
#pragma unroll
        for (int u = 0; u < 4; u++) {
            int s = __float_as_int(e0[u].x);
            hv[u] = *(const float4*)&h[(size_t)s * D + 4 * f4];
        }
#pragma unroll
        for (int u = 0; u < 4; u++) {
            int ku = k + 4 * u;
            float A = (layer == 0) ? e0[u].y : ((layer == 1) ? e0[u].z : e0[u].w);
            float B = (layer == 0) ? e1[u].x : ((layer == 1) ? e1[u].y : e1[u].z);
            if (ku >= n) { A = 0.f; B = 0.f; }
            acc.x += A * hv[u].x; acc.y += A * hv[u].y;
            acc.z += A * hv[u].z; acc.w += A * hv[u].w;
            sA += A; sB += B;
        }
    }
    // combine worker pairs within wave (lanes l and l^32)
    acc.x += __shfl_xor(acc.x, 32); acc.y += __shfl_xor(acc.y, 32);
    acc.z += __shfl_xor(acc.z, 32); acc.w += __shfl_xor(acc.w, 32);
    sA += __shfl_xor(sA, 32); sB += __shfl_xor(sB, 32);
    // cross-wave combine via LDS: upper wave of each node writes, lower reads
    if (((local >> 6) & 1) == 1 && (t & 63) < 32) {
        rbuf[nb][f4] = acc;
        if (f4 == 0) { rsum[nb][0] = sA; rsum[nb][1] = sB; }
    }
    __syncthreads();
    if (((local >> 6) & 1) == 0 && (t & 63) < 32) {
        float4 o = rbuf[nb][f4];
        float sAt = sA + rsum[nb][0];
        float sBt = sB + rsum[nb][1];
        float4 hd = *(const float4*)&h[(size_t)p * D + 4 * f4];
        float4 r;
        r.x = acc.x + o.x - sAt * hd.x + sBt;
        r.y = acc.y + o.y - sAt * hd.y + sBt;
        r.z = acc.z + o.z - sAt * hd.z + sBt;
        r.w = acc.w + o.w - sAt * hd.w + sBt;
        *(float4*)&aggr[(size_t)p * D + 4 * f4] = r;
    }
}

// ------------- node transform + ReLU + LayerNorm + residual --------------------------
// MFMA split-f16 GEMM: one wave owns a 32x128 output tile; no LDS, no barriers.
__global__ __launch_bounds__(256) void k_node(const float* __restrict__ aggr,
                                              const float* __restrict__ hprev,
                                              const float* __restrict__ Wg,   // node_W + l*NT*D*D
                                              const float* __restrict__ bg,   // node_b + l*NT*D
                                              const float* __restrict__ lng,
                                              const float* __restrict__ lnb,
                                              const int* __restrict__ meta,
                                              float* __restrict__ hnext) {
    int wid  = threadIdx.x >> 6;
    int lane = threadIdx.x & 63;
    int w0 = (blockIdx.x * 4 + wid) * 32;          // first row of this wave's tile
    if (w0 >= NPAD) return;
    int l15 = lane & 15, lg = lane >> 4;
    int tt = (w0 >= meta[3]) ? 1 : 0;              // meta[3] is 64-aligned, w0 is 32-aligned
    const float* W = Wg + (size_t)tt * D * D;

    f32x4 acc[2][8];
#pragma unroll
    for (int i = 0; i < 2; i++)
#pragma unroll
        for (int j = 0; j < 8; j++) acc[i][j] = (f32x4){0.f, 0.f, 0.f, 0.f};

#pragma unroll 1
    for (int ks = 0; ks < 4; ks++) {
        int kb = ks * 32 + 8 * lg;                 // float offset within row
        float4 rA[2][2], rB[8][2];
#pragma unroll
        for (int i = 0; i < 2; i++) {
            const float* p = aggr + (size_t)(w0 + 16 * i + l15) * D + kb;
            rA[i][0] = *(const float4*)p;
            rA[i][1] = *(const float4*)(p + 4);
        }
#pragma unroll
        for (int j = 0; j < 8; j++) {
            const float* p = W + (size_t)(16 * j + l15) * D + kb;
            rB[j][0] = *(const float4*)p;
            rB[j][1] = *(const float4*)(p + 4);
        }
        f16x8 ahi[2], alo[2];
#pragma unroll
        for (int i = 0; i < 2; i++) cvt8(rA[i][0], rA[i][1], ahi[i], alo[i]);
#pragma unroll
        for (int j = 0; j < 8; j++) {
            f16x8 bhi, blo;
            cvt8(rB[j][0], rB[j][1], bhi, blo);
#pragma unroll
            for (int i = 0; i < 2; i++) {
                acc[i][j] = __builtin_amdgcn_mfma_f32_16x16x32_f16(ahi[i], bhi, acc[i][j], 0, 0, 0);
                acc[i][j] = __builtin_amdgcn_mfma_f32_16x16x32_f16(alo[i], bhi, acc[i][j], 0, 0, 0);
                acc[i][j] = __builtin_amdgcn_mfma_f32_16x16x32_f16(ahi[i], blo, acc[i][j], 0, 0, 0);
            }
        }
    }

    // epilogue: bias + relu + LN (wave-local: full 128-wide row lives in one 16-lane group) + residual
    float bv[8], gv[8], bb[8];
#pragma unroll
    for (int j = 0; j < 8; j++) {
        int col = 16 * j + l15;
        bv[j] = bg[tt * D + col];
        gv[j] = lng[col];
        bb[j] = lnb[col];
    }
#pragma unroll
    for (int i = 0; i < 2; i++)
#pragma unroll
        for (int j = 0; j < 8; j++)
#pragma unroll
            for (int r = 0; r < 4; r++)
                acc[i][j][r] = fmaxf(acc[i][j][r] + bv[j], 0.f);

    float mu[2][4], rs[2][4];
#pragma unroll
    for (int i = 0; i < 2; i++)
#pragma unroll
        for (int r = 0; r < 4; r++) {
            float s = 0.f, s2 = 0.f;
#pragma unroll
            for (int j = 0; j < 8; j++) { float v = acc[i][j][r]; s += v; s2 += v * v; }
#pragma unroll
            for (int m = 1; m < 16; m <<= 1) { s += __shfl_xor(s, m); s2 += __shfl_xor(s2, m); }
            float mm = s * (1.f / 128.f);
            mu[i][r] = mm;
            rs[i][r] = rsqrtf(s2 * (1.f / 128.f) - mm * mm + 1e-5f);
        }

#pragma unroll
    for (int i = 0; i < 2; i++)
#pragma unroll
        for (int r = 0; r < 4; r++) {
            int row = w0 + 16 * i + 4 * lg + r;
#pragma unroll
            for (int j = 0; j < 8; j++) {
                int col = 16 * j + l15;
                float v = (acc[i][j][r] - mu[i][r]) * rs[i][r] * gv[j] + bb[j]
                          + hprev[(size_t)row * D + col];
                hnext[(size_t)row * D + col] = v;
            }
        }
}

// ------------- final FC with un-permute (same MFMA structure, scatter epilogue) -------------
__global__ __launch_bounds__(256) void k_fc(const float* __restrict__ hin,
                                            const float* __restrict__ W,
                                            const float* __restrict__ bias,
                                            const int* __restrict__ inv,
                                            float* __restrict__ out) {
    int wid  = threadIdx.x >> 6;
    int lane = threadIdx.x & 63;
    int w0 = (blockIdx.x * 4 + wid) * 32;
    if (w0 >= NPAD) return;
    int l15 = lane & 15, lg = lane >> 4;

    f32x4 acc[2][8];
#pragma unroll
    for (int i = 0; i < 2; i++)
#pragma unroll
        for (int j = 0; j < 8; j++) acc[i][j] = (f32x4){0.f, 0.f, 0.f, 0.f};

#pragma unroll 1
    for (int ks = 0; ks < 4; ks++) {
        int kb = ks * 32 + 8 * lg;
        float4 rA[2][2], rB[8][2];
#pragma unroll
        for (int i = 0; i < 2; i++) {
            const float* p = hin + (size_t)(w0 + 16 * i + l15) * D + kb;
            rA[i][0] = *(const float4*)p;
            rA[i][1] = *(const float4*)(p + 4);
        }
#pragma unroll
        for (int j = 0; j < 8; j++) {
            const float* p = W + (size_t)(16 * j + l15) * D + kb;
            rB[j][0] = *(const float4*)p;
            rB[j][1] = *(const float4*)(p + 4);
        }
        f16x8 ahi[2], alo[2];
#pragma unroll
        for (int i = 0; i < 2; i++) cvt8(rA[i][0], rA[i][1], ahi[i], alo[i]);
#pragma unroll
        for (int j = 0; j < 8; j++) {
            f16x8 bhi, blo;
            cvt8(rB[j][0], rB[j][1], bhi, blo);
#pragma unroll
            for (int i = 0; i < 2; i++) {
                acc[i][j] = __builtin_amdgcn_mfma_f32_16x16x32_f16(ahi[i], bhi, acc[i][j], 0, 0, 0);
                acc[i][j] = __builtin_amdgcn_mfma_f32_16x16x32_f16(alo[i], bhi, acc[i][j], 0, 0, 0);
                acc[i][j] = __builtin_amdgcn_mfma_f32_16x16x32_f16(ahi[i], blo, acc[i][j], 0, 0, 0);
            }
        }
    }

    float bv[8];
#pragma unroll
    for (int j = 0; j < 8; j++) bv[j] = bias[16 * j + l15];

#pragma unroll
    for (int i = 0; i < 2; i++)
#pragma unroll
        for (int r = 0; r < 4; r++) {
            int row = w0 + 16 * i + 4 * lg + r;
            int orig = inv[row];
            if (orig >= 0) {
#pragma unroll
                for (int j = 0; j < 8; j++)
                    out[(size_t)orig * D + 16 * j + l15] = acc[i][j][r] + bv[j];
            }
        }
}

extern "C" void kernel_launch(void* const* d_in, const int* in_sizes, int n_in,
                              void* d_out, int out_size, void* d_ws, size_t ws_size,
                              hipStream_t stream) {
    const float* x         = (const float*)d_in[0];
    const float* edge_attr = (const float*)d_in[1];
    const float* node_W    = (const float*)d_in[2];
    const float* node_b    = (const float*)d_in[3];
    const float* edge_W    = (const float*)d_in[4];
    const float* edge_b    = (const float*)d_in[5];
    const float* emb       = (const float*)d_in[6];
    const float* ln_g      = (const float*)d_in[7];
    const float* ln_b      = (const float*)d_in[8];
    const float* fc_W      = (const float*)d_in[9];
    const float* fc_b      = (const float*)d_in[10];
    const int*   edge_index = (const int*)d_in[11];
    const int*   node_type  = (const int*)d_in[12];
    const int*   edge_type  = (const int*)d_in[13];
    float* out = (float*)d_out;

    char* w = (char*)d_ws;
    auto alloc = [&](size_t bytes) {
        void* p = (void*)w;
        w += (bytes + 255) & ~(size_t)255;
        return p;
    };
    float*  P     = (float*)alloc((size_t)NPAD * D * 4);   // permuted x / layer buffers
    float*  Q     = (float*)alloc((size_t)NPAD * D * 4);
    float*  G     = (float*)alloc((size_t)NPAD * D * 4);   // aggr
    float4* esort = (float4*)alloc((size_t)EE * 32);       // 32B records (sp,A0,A1,A2 | B0,B1,B2,-)
    int*    rank  = (int*)alloc((size_t)EE * 4);           // within-destination rank
    int*    pos   = (int*)alloc((size_t)NN * 4);
    int*    inv   = (int*)alloc((size_t)NPAD * 4);
    int*    deg   = (int*)alloc((size_t)NN * 4);
    int*    offs  = (int*)alloc((size_t)NN * 4);
    int*    bsum  = (int*)alloc(256 * 4);
    int*    boff  = (int*)alloc(256 * 4);
    int*    pc    = (int*)alloc(256 * 4);
    int*    po    = (int*)alloc(256 * 4);
    int*    meta  = (int*)alloc(8 * 4);

    hipMemsetAsync(deg, 0, (size_t)NN * 4, stream);
    hipMemsetAsync(inv, 0xFF, (size_t)NPAD * 4, stream);   // -1 = "gap row", k_fc skips

    k_pcount<<<NB, 256, 0, stream>>>(node_type, pc);
    k_pscan<<<1, 256, 0, stream>>>(pc, po, meta);
    k_passign<<<NB, 256, 0, stream>>>(node_type, po, meta, pos, inv);
    k_permx<<<(NN * 32 + 255) / 256, 256, 0, stream>>>(x, pos, P);

    k_hist<<<(EE + 255) / 256, 256, 0, stream>>>(edge_index + EE, deg, rank);
    k_scan_bsum<<<NB, 256, 0, stream>>>(deg, bsum);
    k_scan_boff<<<1, 256, 0, stream>>>(bsum, boff);
    k_scan_offs<<<NB, 256, 0, stream>>>(deg, boff, offs);
    k_edge<<<(EE + 255) / 256, 256, 0, stream>>>(edge_attr, edge_W, edge_b, emb,
                                                 edge_index, edge_type, pos, offs, rank, esort);

    // layer rotation: P -> Q -> P -> Q   (in, out per layer)
    const float* hin = P;
    float* outs[LL] = {Q, P, Q};
    for (int l = 0; l < LL; l++) {
        k_gather<<<NN / 2, 256, 0, stream>>>(hin, offs, deg, pos, esort, l, G);
        k_node<<<NBLKM, 256, 0, stream>>>(G, hin,
                                          node_W + (size_t)l * NT * D * D,
                                          node_b + (size_t)l * NT * D,
                                          ln_g + (size_t)l * D,
                                          ln_b + (size_t)l * D,
                                          meta, outs[l]);
        hin = outs[l];
    }
    k_fc<<<NBLKM, 256, 0, stream>>>(hin, fc_W, fc_b, inv, out);
}